// Round 1
// 131.436 us; speedup vs baseline: 1.0474x; 1.0474x over previous
//
#include <hip/hip_runtime.h>
#include <cstdint>
#include <cstddef>

typedef __attribute__((ext_vector_type(8))) short short8;
typedef __attribute__((ext_vector_type(4))) float f32x4;

#define QSCALE 0.18033688011112043f  // 0.125 * log2(e)

__device__ __forceinline__ float bf2f(unsigned short u) {
  return __uint_as_float(((unsigned)u) << 16);
}
__device__ __forceinline__ unsigned short f2bf(float f) {
  unsigned u = __float_as_uint(f);
  u += 0x7fffu + ((u >> 16) & 1u);
  return (unsigned short)(u >> 16);
}
// pack two positive f32 -> 2 bf16 (round-half-up) in one u32: lo=a, hi=b
__device__ __forceinline__ unsigned packbf2(float a, float b) {
  unsigned ua = __float_as_uint(a) + 0x8000u;
  unsigned ub = __float_as_uint(b) + 0x8000u;
  return __builtin_amdgcn_perm(ub, ua, 0x07060302u);
}
// pack two f32 -> 2 bf16 (RNE) in one VALU op: lo=a, hi=b
__device__ __forceinline__ unsigned cvtpk(float a, float b) {
  unsigned r;
  asm("v_cvt_pk_bf16_f32 %0, %1, %2" : "=v"(r) : "v"(a), "v"(b));
  return r;
}
__device__ __forceinline__ short8 mk8(unsigned a, unsigned b, unsigned c, unsigned d) {
  union { unsigned u[4]; short8 s; } x;
  x.u[0] = a; x.u[1] = b; x.u[2] = c; x.u[3] = d;
  return x.s;
}
__device__ __forceinline__ void g2l16(const void* g, void* l) {
  __builtin_amdgcn_global_load_lds(
      (const __attribute__((address_space(1))) unsigned int*)g,
      (__attribute__((address_space(3))) unsigned int*)l, 16, 0, 0);
}

// ---------------- weight conversion f32 -> bf16 ----------------
__global__ __launch_bounds__(256) void k_wconv(const float* __restrict__ wqf,
                                               const float* __restrict__ wpf,
                                               unsigned short* __restrict__ wq,
                                               unsigned short* __restrict__ wp) {
  int i = blockIdx.x * 256 + threadIdx.x;
  if (i < 196608) {
    float4 v = ((const float4*)wqf)[i];
    ushort4 u;
    u.x = f2bf(v.x); u.y = f2bf(v.y); u.z = f2bf(v.z); u.w = f2bf(v.w);
    ((ushort4*)wq)[i] = u;
  } else {
    int k = i - 196608;
    float4 v = ((const float4*)wpf)[k];
    ushort4 u;
    u.x = f2bf(v.x); u.y = f2bf(v.y); u.z = f2bf(v.z); u.w = f2bf(v.w);
    ((ushort4*)wp)[k] = u;
  }
}

// ---------------- GroupNorm stage 1: partial sums ----------------
__global__ __launch_bounds__(256) void k_gnpart(const float* __restrict__ x,
                                                float* __restrict__ part) {
  int blk = blockIdx.x;
  int bg = blk >> 4, slice = blk & 15;
  const float4* base = (const float4*)(x + (size_t)bg * 65536 + (size_t)slice * 4096);
  int t = threadIdx.x;
  float s = 0.f, q = 0.f;
#pragma unroll
  for (int i = 0; i < 4; ++i) {
    float4 v = base[t + i * 256];
    s += v.x + v.y + v.z + v.w;
    q += v.x * v.x + v.y * v.y + v.z * v.z + v.w * v.w;
  }
#pragma unroll
  for (int off = 1; off < 64; off <<= 1) {
    s += __shfl_xor(s, off);
    q += __shfl_xor(q, off);
  }
  __shared__ float red[8];
  int wid = t >> 6;
  if ((t & 63) == 0) { red[wid * 2] = s; red[wid * 2 + 1] = q; }
  __syncthreads();
  if (t == 0) {
    float S = red[0] + red[2] + red[4] + red[6];
    float Q = red[1] + red[3] + red[5] + red[7];
    part[blk * 2] = S;
    part[blk * 2 + 1] = Q;
  }
}

// ---------------- GroupNorm stage 2 ----------------
__global__ void k_gnfin(const float* __restrict__ part, float* __restrict__ stats) {
  int t = threadIdx.x;
  float S = 0.f, Q = 0.f;
#pragma unroll
  for (int i = 0; i < 16; ++i) {
    S += part[(t * 16 + i) * 2];
    Q += part[(t * 16 + i) * 2 + 1];
  }
  float mean = S * (1.f / 65536.f);
  float var = Q * (1.f / 65536.f) - mean * mean;
  stats[t * 2] = mean;
  stats[t * 2 + 1] = rsqrtf(var + 1e-6f);
}

// ---------------- GroupNorm normalize: xn + xnT ----------------
__global__ __launch_bounds__(256) void k_gnnorm(const float* __restrict__ x,
                                                const float* __restrict__ gnw,
                                                const float* __restrict__ gnb,
                                                const float* __restrict__ stats,
                                                unsigned short* __restrict__ xn,
                                                unsigned short* __restrict__ xnT) {
  __shared__ float T[64 * 65];
  const int t = threadIdx.x;
  const int n0 = blockIdx.x * 64, c0 = blockIdx.y * 64, bb = blockIdx.z;
#pragma unroll
  for (int p = 0; p < 4; ++p) {
    int s = p * 256 + t;
    int row = s >> 4, seg = s & 15;
    int c = c0 + row;
    int gi = bb * 32 + (c >> 4);
    float mean = stats[gi * 2], rstd = stats[gi * 2 + 1];
    float gw = gnw[c] * rstd;
    float gb = gnb[c] - mean * gw;
    float4 v = *(const float4*)(x + ((size_t)bb * 512 + c) * 4096 + n0 + seg * 4);
    float f0 = v.x * gw + gb, f1 = v.y * gw + gb, f2 = v.z * gw + gb, f3 = v.w * gw + gb;
    ushort4 u;
    u.x = f2bf(f0); u.y = f2bf(f1); u.z = f2bf(f2); u.w = f2bf(f3);
    *(ushort4*)(xn + ((size_t)bb * 512 + c) * 4096 + n0 + seg * 4) = u;
    T[(seg * 4 + 0) * 65 + row] = f0;
    T[(seg * 4 + 1) * 65 + row] = f1;
    T[(seg * 4 + 2) * 65 + row] = f2;
    T[(seg * 4 + 3) * 65 + row] = f3;
  }
  __syncthreads();
#pragma unroll
  for (int p = 0; p < 4; ++p) {
    int s = p * 256 + t;
    int nl = s >> 4, cs = s & 15;
    float f0 = T[nl * 65 + cs * 4 + 0];
    float f1 = T[nl * 65 + cs * 4 + 1];
    float f2 = T[nl * 65 + cs * 4 + 2];
    float f3 = T[nl * 65 + cs * 4 + 3];
    ushort4 u;
    u.x = f2bf(f0); u.y = f2bf(f1); u.z = f2bf(f2); u.w = f2bf(f3);
    *(ushort4*)(xnT + ((size_t)bb * 4096 + n0 + nl) * 512 + c0 + cs * 4) = u;
  }
}

// ---------------- GEMM ----------------
// MODE 0 (QKV): qkv gets V rows only, with j bit-permuted within 64-blocks
//               (u5,u4,u3:2,u1:0 -> u5,u3:2,u4,u1:0) so attn PV reads are b128;
//               qkvT gets Q/K rows only. MODE 1 (proj): +bias+resid f32.
template <int MODE>
__global__ __launch_bounds__(256) void k_gemm(
    const unsigned short* __restrict__ A,
    const unsigned short* __restrict__ Bt,
    const float* __restrict__ bias,
    unsigned short* __restrict__ outA,
    unsigned short* __restrict__ outT,
    const unsigned short* __restrict__ resid,
    float* __restrict__ outF,
    int Mo) {
  __shared__ char lds[34816];
  const int t = threadIdx.x;
  const int lane = t & 63;
  const int g = lane >> 4, ln = lane & 15;
  const int wid = t >> 6, wr = wid >> 1, wc = wid & 1;
  const int bn0 = blockIdx.x * 128, bm0 = blockIdx.y * 128, bb = blockIdx.z;

  const unsigned short* Ab = A + (size_t)bm0 * 512;
  const unsigned short* Bb = Bt + ((size_t)bb * 4096 + bn0) * 512;

  f32x4 acc[4][4];
#pragma unroll
  for (int m = 0; m < 4; ++m)
#pragma unroll
    for (int n = 0; n < 4; ++n) acc[m][n] = f32x4{0.f, 0.f, 0.f, 0.f};

#pragma unroll 1
  for (int kt = 0; kt < 8; ++kt) {
#pragma unroll
    for (int p = 0; p < 4; ++p) {
      int s = p * 256 + t;
      int row = s >> 3;
      int csg = (s & 7) ^ (row & 7);
      g2l16(Ab + (size_t)row * 512 + kt * 64 + csg * 8,
            &lds[(p * 256 + (t & ~63)) * 16]);
    }
#pragma unroll
    for (int p = 0; p < 4; ++p) {
      int s = p * 256 + t;
      int row = s >> 3;
      int csg = (s & 7) ^ (row & 7);
      g2l16(Bb + (size_t)row * 512 + kt * 64 + csg * 8,
            &lds[16384 + (p * 256 + (t & ~63)) * 16]);
    }
    __syncthreads();
#pragma unroll
    for (int kk = 0; kk < 2; ++kk) {
      short8 af[4], bfr[4];
#pragma unroll
      for (int m = 0; m < 4; ++m) {
        int row = wr * 64 + m * 16 + ln;
        int cs = (kk * 4 + g) ^ (row & 7);
        af[m] = *(const short8*)&lds[row * 128 + cs * 16];
      }
#pragma unroll
      for (int n = 0; n < 4; ++n) {
        int row = wc * 64 + n * 16 + ln;
        int cs = (kk * 4 + g) ^ (row & 7);
        bfr[n] = *(const short8*)&lds[16384 + row * 128 + cs * 16];
      }
      __builtin_amdgcn_s_setprio(1);
#pragma unroll
      for (int m = 0; m < 4; ++m)
#pragma unroll
        for (int n = 0; n < 4; ++n)
          acc[m][n] = __builtin_amdgcn_mfma_f32_16x16x32_bf16(af[m], bfr[n], acc[m][n], 0, 0, 0);
      __builtin_amdgcn_s_setprio(0);
    }
    __syncthreads();
  }

  if (MODE == 0) {
#pragma unroll
    for (int m = 0; m < 4; ++m)
#pragma unroll
      for (int n = 0; n < 4; ++n)
#pragma unroll
        for (int r = 0; r < 4; ++r) {
          int ol = wr * 64 + m * 16 + g * 4 + r;
          int jl = wc * 64 + n * 16 + ln;
          int o = bm0 + ol, j = bn0 + jl;
          float v = acc[m][n][r] + bias[o];
          unsigned short bv = f2bf(v);
          if ((o % 192) >= 128) {  // V rows only, j bit-permuted within 64-block
            int jp = (j & ~63) | (j & 32) | ((j & 0xC) << 1) | ((j & 16) >> 2) | (j & 3);
            outA[((size_t)bb * 1536 + o) * 4096 + jp] = bv;
          }
          *(unsigned short*)&lds[jl * 272 + ol * 2] = bv;
        }
    __syncthreads();
#pragma unroll
    for (int p = 0; p < 8; ++p) {
      int s = p * 256 + t;
      int jl = s >> 4, cs = s & 15;
      int oo = bm0 + cs * 8;
      if ((oo % 192) < 128) {  // Q,K rows only
        short8 v = *(const short8*)&lds[jl * 272 + cs * 16];
        *(short8*)&outT[((size_t)bb * 4096 + bn0 + jl) * 1536 + oo] = v;
      }
    }
  } else {
#pragma unroll
    for (int m = 0; m < 4; ++m)
#pragma unroll
      for (int n = 0; n < 4; ++n)
#pragma unroll
        for (int r = 0; r < 4; ++r) {
          int o = bm0 + wr * 64 + m * 16 + g * 4 + r;
          int j = bn0 + wc * 64 + n * 16 + ln;
          size_t idx = ((size_t)bb * 512 + o) * 4096 + j;
          outF[idx] = acc[m][n][r] + bias[o] + bf2f(resid[idx]);
        }
  }
}

// ---------------- Flash attention v5: cvt_pk pack + MFMA-ones row sums ----------------
// grid (32 q-tiles of 128, 8 heads, 2 batch) = 512 blocks, 4 waves, wave owns 32 q.
// K/V tiles (64 j x 64 d) TRIPLE-buffered (48 KB LDS); ONE barrier per iter:
//   [vmcnt(4) tile j landed] -> barrier -> [stage tile j+2] -> compute tile j.
// V is stored j-bit-permuted by k_gemm<0> so PV B-fragments are straight b128
// swizzled reads (same conflict-free pattern as K).
// VALU diet vs v4:
//  - p-pack: v_cvt_pk_bf16_f32 (1 op/pair) instead of packbf2 (3 ops/pair)
//  - row-sums: extra MFMA of pf against all-ones B frag -> lacc holds the FULL
//    per-q-row sum (MFMA reduces over k AND across the 4 g-group lane copies),
//    in the same C/D layout as acc -> no per-iter v_adds, no epilogue shuffles
//  - QK zero-init folded into first-kk MFMA (C = const zero)
__global__ __launch_bounds__(256, 2) void k_attn(const unsigned short* __restrict__ qkv,
                                                 const unsigned short* __restrict__ qkvT,
                                                 unsigned short* __restrict__ aT) {
  __shared__ char lds[49152];  // K: cur*8192, V: 24576 + cur*8192
  const int t = threadIdx.x, lane = t & 63;
  const int g = lane >> 4, ln = lane & 15;
  const int wid = t >> 6;
  const int h = blockIdx.y, bb = blockIdx.z;
  const int q0 = blockIdx.x * 128 + wid * 32;

  // LDS byte offsets for K/V fragment reads (identical swizzled b128 pattern)
  int kaddr[2][4], vaddr[2][4];
#pragma unroll
  for (int kk = 0; kk < 2; ++kk)
#pragma unroll
    for (int f = 0; f < 4; ++f) {
      int row = f * 16 + ln;
      int off = row * 128 + (((kk * 4 + g) ^ (row & 7)) << 4);
      kaddr[kk][f] = off;
      vaddr[kk][f] = 24576 + off;
    }

  // staging source pointers (advance by one tile per stage)
  const unsigned short* kS[2];
  const unsigned short* vS[2];
  int ldst[2];
#pragma unroll
  for (int p = 0; p < 2; ++p) {
    int s = p * 256 + t;
    int row = s >> 3, csg = (s & 7) ^ (row & 7);
    kS[p] = qkvT + ((size_t)bb * 4096 + row) * 1536 + 192 * h + 64 + csg * 8;
    vS[p] = qkv + ((size_t)bb * 1536 + 192 * h + 128 + row) * 4096 + csg * 8;
    ldst[p] = (p * 256 + (t & ~63)) * 16;
  }

  // Q fragments [qt][kk], pre-scaled by 0.125*log2(e)
  short8 qf[2][2];
#pragma unroll
  for (int qt = 0; qt < 2; ++qt)
#pragma unroll
    for (int kk = 0; kk < 2; ++kk) {
      short8 v = *(const short8*)(qkvT + ((size_t)bb * 4096 + q0 + qt * 16 + ln) * 1536 +
                                  192 * h + kk * 32 + g * 8);
#pragma unroll
      for (int e = 0; e < 8; ++e) {
        float f = bf2f((unsigned short)v[e]) * QSCALE;
        v[e] = (short)f2bf(f);
      }
      qf[qt][kk] = v;
    }

  // all-ones bf16 B fragment for the row-sum MFMA
  const short8 onesb = mk8(0x3F803F80u, 0x3F803F80u, 0x3F803F80u, 0x3F803F80u);

  f32x4 acc[2][4];
  f32x4 lacc[2];
#pragma unroll
  for (int qt = 0; qt < 2; ++qt) {
#pragma unroll
    for (int df = 0; df < 4; ++df) acc[qt][df] = f32x4{0.f, 0.f, 0.f, 0.f};
    lacc[qt] = f32x4{0.f, 0.f, 0.f, 0.f};
  }

  // prologue: stage tiles 0 (buf0) and 1 (buf1)
#pragma unroll
  for (int jt = 0; jt < 2; ++jt) {
#pragma unroll
    for (int p = 0; p < 2; ++p) {
      g2l16(kS[p], &lds[jt * 8192 + ldst[p]]);
      g2l16(vS[p], &lds[24576 + jt * 8192 + ldst[p]]);
      kS[p] += 64 * 1536;
      vS[p] += 64;
    }
  }

#pragma unroll 3
  for (int jt = 0; jt < 64; ++jt) {
    const int cur = jt % 3;
    const char* Kc = &lds[cur * 8192];
    const char* Vc = &lds[cur * 8192];  // vaddr carries the 24576 base
    if (jt < 63) {
      asm volatile("s_waitcnt vmcnt(4)" ::: "memory");
    } else {
      asm volatile("s_waitcnt vmcnt(0)" ::: "memory");
    }
    __builtin_amdgcn_s_barrier();
    __builtin_amdgcn_sched_barrier(0);

    // stage tile jt+2 into buf (jt+2)%3 (safe: all waves passed barrier jt)
    if (jt < 62) {
      int nb = (jt + 2) % 3;
#pragma unroll
      for (int p = 0; p < 2; ++p) {
        g2l16(kS[p], &lds[nb * 8192 + ldst[p]]);
        g2l16(vS[p], &lds[24576 + nb * 8192 + ldst[p]]);
        kS[p] += 64 * 1536;
        vS[p] += 64;
      }
    }

    // K & V fragments (b128, conflict-free)
    short8 kf[2][4], vf[2][4];
#pragma unroll
    for (int kk = 0; kk < 2; ++kk)
#pragma unroll
      for (int f = 0; f < 4; ++f) {
        kf[kk][f] = *(const short8*)(Kc + kaddr[kk][f]);
        vf[kk][f] = *(const short8*)(Vc + vaddr[kk][f]);
      }

#pragma unroll
    for (int qt = 0; qt < 2; ++qt) {
      f32x4 w[4];
      const f32x4 zf = f32x4{0.f, 0.f, 0.f, 0.f};
      __builtin_amdgcn_s_setprio(1);
#pragma unroll
      for (int jf = 0; jf < 4; ++jf)
        w[jf] = __builtin_amdgcn_mfma_f32_16x16x32_bf16(kf[0][jf], qf[qt][0], zf, 0, 0, 0);
#pragma unroll
      for (int jf = 0; jf < 4; ++jf)
        w[jf] = __builtin_amdgcn_mfma_f32_16x16x32_bf16(kf[1][jf], qf[qt][1], w[jf], 0, 0, 0);
      __builtin_amdgcn_s_setprio(0);

      // p = exp2(w) via raw v_exp_f32 (args >= -15: denorm path unreachable)
#pragma unroll
      for (int jf = 0; jf < 4; ++jf)
#pragma unroll
        for (int r = 0; r < 4; ++r)
          w[jf][r] = __builtin_amdgcn_exp2f(w[jf][r]);

      // pack to bf16: one v_cvt_pk_bf16_f32 per pair (RNE)
      short8 pf[2];
#pragma unroll
      for (int kk = 0; kk < 2; ++kk)
        pf[kk] = mk8(cvtpk(w[2 * kk][0], w[2 * kk][1]),
                     cvtpk(w[2 * kk][2], w[2 * kk][3]),
                     cvtpk(w[2 * kk + 1][0], w[2 * kk + 1][1]),
                     cvtpk(w[2 * kk + 1][2], w[2 * kk + 1][3]));

      __builtin_amdgcn_s_setprio(1);
#pragma unroll
      for (int kk = 0; kk < 2; ++kk) {
#pragma unroll
        for (int df = 0; df < 4; ++df)
          acc[qt][df] = __builtin_amdgcn_mfma_f32_16x16x32_bf16(pf[kk], vf[kk][df], acc[qt][df], 0, 0, 0);
        // row-sum: D[q][*] += sum_k pf -- full reduction incl. cross-g copies
        lacc[qt] = __builtin_amdgcn_mfma_f32_16x16x32_bf16(pf[kk], onesb, lacc[qt], 0, 0, 0);
      }
      __builtin_amdgcn_s_setprio(0);
    }
  }

  // epilogue: lacc already holds full row sums in acc's C/D layout -> no shuffles
#pragma unroll
  for (int qt = 0; qt < 2; ++qt) {
#pragma unroll
    for (int r = 0; r < 4; ++r) {
      float inv = 1.f / lacc[qt][r];
      int row = q0 + qt * 16 + g * 4 + r;
#pragma unroll
      for (int df = 0; df < 4; ++df)
        aT[((size_t)bb * 4096 + row) * 512 + h * 64 + df * 16 + ln] =
            f2bf(acc[qt][df][r] * inv);
    }
  }
}

// ---------------- launcher ----------------
extern "C" void kernel_launch(void* const* d_in, const int* in_sizes, int n_in,
                              void* d_out, int out_size, void* d_ws, size_t ws_size,
                              hipStream_t stream) {
  const float* x     = (const float*)d_in[0];
  const float* gnw   = (const float*)d_in[1];
  const float* gnb   = (const float*)d_in[2];
  const float* qkvw  = (const float*)d_in[3];
  const float* qkvb  = (const float*)d_in[4];
  const float* projw = (const float*)d_in[5];
  const float* projb = (const float*)d_in[6];
  float* out = (float*)d_out;
  char* ws = (char*)d_ws;

  const size_t OFF_WQ   = 0;
  const size_t OFF_WP   = 1572864;
  const size_t OFF_XN   = 2097152;
  const size_t OFF_XNT  = 10485760;
  const size_t OFF_QKV  = 18874368;
  const size_t OFF_QKVT = 44040192;
  const size_t OFF_AT   = 69206016;
  const size_t OFF_PART = 77594624;
  const size_t OFF_STAT = 77602816;

  unsigned short* wq   = (unsigned short*)(ws + OFF_WQ);
  unsigned short* wp   = (unsigned short*)(ws + OFF_WP);
  unsigned short* xn   = (unsigned short*)(ws + OFF_XN);
  unsigned short* xnT  = (unsigned short*)(ws + OFF_XNT);
  unsigned short* qkv  = (unsigned short*)(ws + OFF_QKV);
  unsigned short* qkvT = (unsigned short*)(ws + OFF_QKVT);
  unsigned short* aT   = (unsigned short*)(ws + OFF_AT);
  float* part  = (float*)(ws + OFF_PART);
  float* stats = (float*)(ws + OFF_STAT);

  k_wconv<<<dim3(1024), dim3(256), 0, stream>>>(qkvw, projw, wq, wp);
  k_gnpart<<<dim3(1024), dim3(256), 0, stream>>>(x, part);
  k_gnfin<<<dim3(1), dim3(64), 0, stream>>>(part, stats);
  k_gnnorm<<<dim3(64, 8, 2), dim3(256), 0, stream>>>(x, gnw, gnb, stats, xn, xnT);
  k_gemm<0><<<dim3(32, 12, 2), dim3(256), 0, stream>>>(wq, xnT, qkvb, qkv, qkvT, nullptr, nullptr, 1536);
  k_attn<<<dim3(32, 8, 2), dim3(256), 0, stream>>>(qkv, qkvT, aT);
  k_gemm<1><<<dim3(32, 4, 2), dim3(256), 0, stream>>>(wp, aT, projb, nullptr, nullptr, xn, out, 512);
}

// Round 2
// 125.621 us; speedup vs baseline: 1.0958x; 1.0463x over previous
//
#include <hip/hip_runtime.h>
#include <cstdint>
#include <cstddef>

typedef __attribute__((ext_vector_type(8))) short short8;
typedef __attribute__((ext_vector_type(4))) float f32x4;

#define QSCALE 0.18033688011112043f  // 0.125 * log2(e)

__device__ __forceinline__ float bf2f(unsigned short u) {
  return __uint_as_float(((unsigned)u) << 16);
}
__device__ __forceinline__ unsigned short f2bf(float f) {
  unsigned u = __float_as_uint(f);
  u += 0x7fffu + ((u >> 16) & 1u);
  return (unsigned short)(u >> 16);
}
// pack two f32 -> 2 bf16 (RNE) in one VALU op: lo=a, hi=b
__device__ __forceinline__ unsigned cvtpk(float a, float b) {
  unsigned r;
  asm("v_cvt_pk_bf16_f32 %0, %1, %2" : "=v"(r) : "v"(a), "v"(b));
  return r;
}
__device__ __forceinline__ short8 mk8(unsigned a, unsigned b, unsigned c, unsigned d) {
  union { unsigned u[4]; short8 s; } x;
  x.u[0] = a; x.u[1] = b; x.u[2] = c; x.u[3] = d;
  return x.s;
}
__device__ __forceinline__ void g2l16(const void* g, void* l) {
  __builtin_amdgcn_global_load_lds(
      (const __attribute__((address_space(1))) unsigned int*)g,
      (__attribute__((address_space(3))) unsigned int*)l, 16, 0, 0);
}

// ---------------- fused: weight conversion + GroupNorm partial sums ----------------
// blocks [0,1024): f32->bf16 weight convert; blocks [1024,2048): GN partial sums.
__global__ __launch_bounds__(256) void k_wgn(const float* __restrict__ wqf,
                                             const float* __restrict__ wpf,
                                             unsigned short* __restrict__ wq,
                                             unsigned short* __restrict__ wp,
                                             const float* __restrict__ x,
                                             float* __restrict__ part) {
  __shared__ float red[8];
  const int blk = blockIdx.x;
  const int t = threadIdx.x;
  if (blk < 1024) {
    int i = blk * 256 + t;
    if (i < 196608) {
      float4 v = ((const float4*)wqf)[i];
      ushort4 u;
      u.x = f2bf(v.x); u.y = f2bf(v.y); u.z = f2bf(v.z); u.w = f2bf(v.w);
      ((ushort4*)wq)[i] = u;
    } else {
      int k = i - 196608;
      float4 v = ((const float4*)wpf)[k];
      ushort4 u;
      u.x = f2bf(v.x); u.y = f2bf(v.y); u.z = f2bf(v.z); u.w = f2bf(v.w);
      ((ushort4*)wp)[k] = u;
    }
  } else {
    int b2 = blk - 1024;
    int bg = b2 >> 4, slice = b2 & 15;
    const float4* base = (const float4*)(x + (size_t)bg * 65536 + (size_t)slice * 4096);
    float s = 0.f, q = 0.f;
#pragma unroll
    for (int i = 0; i < 4; ++i) {
      float4 v = base[t + i * 256];
      s += v.x + v.y + v.z + v.w;
      q += v.x * v.x + v.y * v.y + v.z * v.z + v.w * v.w;
    }
#pragma unroll
    for (int off = 1; off < 64; off <<= 1) {
      s += __shfl_xor(s, off);
      q += __shfl_xor(q, off);
    }
    int wid = t >> 6;
    if ((t & 63) == 0) { red[wid * 2] = s; red[wid * 2 + 1] = q; }
    __syncthreads();
    if (t == 0) {
      float S = red[0] + red[2] + red[4] + red[6];
      float Q = red[1] + red[3] + red[5] + red[7];
      part[b2 * 2] = S;
      part[b2 * 2 + 1] = Q;
    }
  }
}

// ---------------- GroupNorm stage 2 ----------------
__global__ void k_gnfin(const float* __restrict__ part, float* __restrict__ stats) {
  int t = threadIdx.x;
  float S = 0.f, Q = 0.f;
#pragma unroll
  for (int i = 0; i < 16; ++i) {
    S += part[(t * 16 + i) * 2];
    Q += part[(t * 16 + i) * 2 + 1];
  }
  float mean = S * (1.f / 65536.f);
  float var = Q * (1.f / 65536.f) - mean * mean;
  stats[t * 2] = mean;
  stats[t * 2 + 1] = rsqrtf(var + 1e-6f);
}

// ---------------- GroupNorm normalize: xn + xnT ----------------
__global__ __launch_bounds__(256) void k_gnnorm(const float* __restrict__ x,
                                                const float* __restrict__ gnw,
                                                const float* __restrict__ gnb,
                                                const float* __restrict__ stats,
                                                unsigned short* __restrict__ xn,
                                                unsigned short* __restrict__ xnT) {
  __shared__ float T[64 * 65];
  const int t = threadIdx.x;
  const int n0 = blockIdx.x * 64, c0 = blockIdx.y * 64, bb = blockIdx.z;
#pragma unroll
  for (int p = 0; p < 4; ++p) {
    int s = p * 256 + t;
    int row = s >> 4, seg = s & 15;
    int c = c0 + row;
    int gi = bb * 32 + (c >> 4);
    float mean = stats[gi * 2], rstd = stats[gi * 2 + 1];
    float gw = gnw[c] * rstd;
    float gb = gnb[c] - mean * gw;
    float4 v = *(const float4*)(x + ((size_t)bb * 512 + c) * 4096 + n0 + seg * 4);
    float f0 = v.x * gw + gb, f1 = v.y * gw + gb, f2 = v.z * gw + gb, f3 = v.w * gw + gb;
    ushort4 u;
    u.x = f2bf(f0); u.y = f2bf(f1); u.z = f2bf(f2); u.w = f2bf(f3);
    *(ushort4*)(xn + ((size_t)bb * 512 + c) * 4096 + n0 + seg * 4) = u;
    T[(seg * 4 + 0) * 65 + row] = f0;
    T[(seg * 4 + 1) * 65 + row] = f1;
    T[(seg * 4 + 2) * 65 + row] = f2;
    T[(seg * 4 + 3) * 65 + row] = f3;
  }
  __syncthreads();
#pragma unroll
  for (int p = 0; p < 4; ++p) {
    int s = p * 256 + t;
    int nl = s >> 4, cs = s & 15;
    float f0 = T[nl * 65 + cs * 4 + 0];
    float f1 = T[nl * 65 + cs * 4 + 1];
    float f2 = T[nl * 65 + cs * 4 + 2];
    float f3 = T[nl * 65 + cs * 4 + 3];
    ushort4 u;
    u.x = f2bf(f0); u.y = f2bf(f1); u.z = f2bf(f2); u.w = f2bf(f3);
    *(ushort4*)(xnT + ((size_t)bb * 4096 + n0 + nl) * 512 + c0 + cs * 4) = u;
  }
}

// ---------------- GEMM ----------------
// MODE 0 (QKV): qkv gets V rows only, with j bit-permuted within 64-blocks
//               (u5,u4,u3:2,u1:0 -> u5,u3:2,u4,u1:0) so attn PV reads are b128;
//               qkvT gets Q/K rows only. MODE 1 (proj): +bias+resid f32.
template <int MODE>
__global__ __launch_bounds__(256) void k_gemm(
    const unsigned short* __restrict__ A,
    const unsigned short* __restrict__ Bt,
    const float* __restrict__ bias,
    unsigned short* __restrict__ outA,
    unsigned short* __restrict__ outT,
    const unsigned short* __restrict__ resid,
    float* __restrict__ outF,
    int Mo) {
  __shared__ char lds[34816];
  const int t = threadIdx.x;
  const int lane = t & 63;
  const int g = lane >> 4, ln = lane & 15;
  const int wid = t >> 6, wr = wid >> 1, wc = wid & 1;
  const int bn0 = blockIdx.x * 128, bm0 = blockIdx.y * 128, bb = blockIdx.z;

  const unsigned short* Ab = A + (size_t)bm0 * 512;
  const unsigned short* Bb = Bt + ((size_t)bb * 4096 + bn0) * 512;

  f32x4 acc[4][4];
#pragma unroll
  for (int m = 0; m < 4; ++m)
#pragma unroll
    for (int n = 0; n < 4; ++n) acc[m][n] = f32x4{0.f, 0.f, 0.f, 0.f};

#pragma unroll 1
  for (int kt = 0; kt < 8; ++kt) {
#pragma unroll
    for (int p = 0; p < 4; ++p) {
      int s = p * 256 + t;
      int row = s >> 3;
      int csg = (s & 7) ^ (row & 7);
      g2l16(Ab + (size_t)row * 512 + kt * 64 + csg * 8,
            &lds[(p * 256 + (t & ~63)) * 16]);
    }
#pragma unroll
    for (int p = 0; p < 4; ++p) {
      int s = p * 256 + t;
      int row = s >> 3;
      int csg = (s & 7) ^ (row & 7);
      g2l16(Bb + (size_t)row * 512 + kt * 64 + csg * 8,
            &lds[16384 + (p * 256 + (t & ~63)) * 16]);
    }
    __syncthreads();
#pragma unroll
    for (int kk = 0; kk < 2; ++kk) {
      short8 af[4], bfr[4];
#pragma unroll
      for (int m = 0; m < 4; ++m) {
        int row = wr * 64 + m * 16 + ln;
        int cs = (kk * 4 + g) ^ (row & 7);
        af[m] = *(const short8*)&lds[row * 128 + cs * 16];
      }
#pragma unroll
      for (int n = 0; n < 4; ++n) {
        int row = wc * 64 + n * 16 + ln;
        int cs = (kk * 4 + g) ^ (row & 7);
        bfr[n] = *(const short8*)&lds[16384 + row * 128 + cs * 16];
      }
      __builtin_amdgcn_s_setprio(1);
#pragma unroll
      for (int m = 0; m < 4; ++m)
#pragma unroll
        for (int n = 0; n < 4; ++n)
          acc[m][n] = __builtin_amdgcn_mfma_f32_16x16x32_bf16(af[m], bfr[n], acc[m][n], 0, 0, 0);
      __builtin_amdgcn_s_setprio(0);
    }
    __syncthreads();
  }

  if (MODE == 0) {
#pragma unroll
    for (int m = 0; m < 4; ++m)
#pragma unroll
      for (int n = 0; n < 4; ++n)
#pragma unroll
        for (int r = 0; r < 4; ++r) {
          int ol = wr * 64 + m * 16 + g * 4 + r;
          int jl = wc * 64 + n * 16 + ln;
          int o = bm0 + ol, j = bn0 + jl;
          float v = acc[m][n][r] + bias[o];
          unsigned short bv = f2bf(v);
          if ((o % 192) >= 128) {  // V rows only, j bit-permuted within 64-block
            int jp = (j & ~63) | (j & 32) | ((j & 0xC) << 1) | ((j & 16) >> 2) | (j & 3);
            outA[((size_t)bb * 1536 + o) * 4096 + jp] = bv;
          }
          *(unsigned short*)&lds[jl * 272 + ol * 2] = bv;
        }
    __syncthreads();
#pragma unroll
    for (int p = 0; p < 8; ++p) {
      int s = p * 256 + t;
      int jl = s >> 4, cs = s & 15;
      int oo = bm0 + cs * 8;
      if ((oo % 192) < 128) {  // Q,K rows only
        short8 v = *(const short8*)&lds[jl * 272 + cs * 16];
        *(short8*)&outT[((size_t)bb * 4096 + bn0 + jl) * 1536 + oo] = v;
      }
    }
  } else {
#pragma unroll
    for (int m = 0; m < 4; ++m)
#pragma unroll
      for (int n = 0; n < 4; ++n)
#pragma unroll
        for (int r = 0; r < 4; ++r) {
          int o = bm0 + wr * 64 + m * 16 + g * 4 + r;
          int j = bn0 + wc * 64 + n * 16 + ln;
          size_t idx = ((size_t)bb * 512 + o) * 4096 + j;
          outF[idx] = acc[m][n][r] + bias[o] + bf2f(resid[idx]);
        }
  }
}

// ---------------- Flash attention v6: software-pipelined exp || PV ----------------
// grid (32 q-tiles of 128, 8 heads, 2 batch) = 512 blocks, 4 waves, wave owns 32 q.
// K/V tiles (64 j x 64 d) TRIPLE-buffered (48 KB LDS); ONE barrier per iter.
// NEW vs v5 (T15 double-pipeline): P(jt-1) and V(jt-1) fragments are carried in
// registers; PV(jt-1)'s 20 MFMAs are interleaved 1:2 with exp(jt)'s 32 trans ops
// (sched_group_barrier-enforced, region fenced from QK by sched_barrier(0)).
// The matrix pipe no longer idles during the exp block. V(jt) is read into regs
// AFTER the interleave; loop-top waitcnt has lgkmcnt(0) so those reads complete
// before any wave's restage of buffer jt%3 (issued after barrier jt+1) can land.
__global__ __launch_bounds__(256, 2) void k_attn(const unsigned short* __restrict__ qkv,
                                                 const unsigned short* __restrict__ qkvT,
                                                 unsigned short* __restrict__ aT) {
  __shared__ char lds[49152];  // K: cur*8192, V: 24576 + cur*8192
  const int t = threadIdx.x, lane = t & 63;
  const int g = lane >> 4, ln = lane & 15;
  const int wid = t >> 6;
  const int h = blockIdx.y, bb = blockIdx.z;
  const int q0 = blockIdx.x * 128 + wid * 32;

  // LDS byte offsets for K/V fragment reads (identical swizzled b128 pattern)
  int kaddr[2][4], vaddr[2][4];
#pragma unroll
  for (int kk = 0; kk < 2; ++kk)
#pragma unroll
    for (int f = 0; f < 4; ++f) {
      int row = f * 16 + ln;
      int off = row * 128 + (((kk * 4 + g) ^ (row & 7)) << 4);
      kaddr[kk][f] = off;
      vaddr[kk][f] = 24576 + off;
    }

  // staging source pointers (advance by one tile per stage)
  const unsigned short* kS[2];
  const unsigned short* vS[2];
  int ldst[2];
#pragma unroll
  for (int p = 0; p < 2; ++p) {
    int s = p * 256 + t;
    int row = s >> 3, csg = (s & 7) ^ (row & 7);
    kS[p] = qkvT + ((size_t)bb * 4096 + row) * 1536 + 192 * h + 64 + csg * 8;
    vS[p] = qkv + ((size_t)bb * 1536 + 192 * h + 128 + row) * 4096 + csg * 8;
    ldst[p] = (p * 256 + (t & ~63)) * 16;
  }

  // Q fragments [qt][kk], pre-scaled by 0.125*log2(e)
  short8 qf[2][2];
#pragma unroll
  for (int qt = 0; qt < 2; ++qt)
#pragma unroll
    for (int kk = 0; kk < 2; ++kk) {
      short8 v = *(const short8*)(qkvT + ((size_t)bb * 4096 + q0 + qt * 16 + ln) * 1536 +
                                  192 * h + kk * 32 + g * 8);
#pragma unroll
      for (int e = 0; e < 8; ++e) {
        float f = bf2f((unsigned short)v[e]) * QSCALE;
        v[e] = (short)f2bf(f);
      }
      qf[qt][kk] = v;
    }

  // all-ones bf16 B fragment for the row-sum MFMA
  const short8 onesb = mk8(0x3F803F80u, 0x3F803F80u, 0x3F803F80u, 0x3F803F80u);

  f32x4 acc[2][4];
  f32x4 lacc[2];
#pragma unroll
  for (int qt = 0; qt < 2; ++qt) {
#pragma unroll
    for (int df = 0; df < 4; ++df) acc[qt][df] = f32x4{0.f, 0.f, 0.f, 0.f};
    lacc[qt] = f32x4{0.f, 0.f, 0.f, 0.f};
  }

  short8 pf[2][2];   // packed P of previous tile [qt][kk]
  short8 vfp[2][4];  // V fragments of previous tile [kk][df]

  // prologue: stage tiles 0 (buf0) and 1 (buf1)
#pragma unroll
  for (int jt = 0; jt < 2; ++jt) {
#pragma unroll
    for (int p = 0; p < 2; ++p) {
      g2l16(kS[p], &lds[jt * 8192 + ldst[p]]);
      g2l16(vS[p], &lds[24576 + jt * 8192 + ldst[p]]);
      kS[p] += 64 * 1536;
      vS[p] += 64;
    }
  }

  // ---- peeled iter 0: QK/exp/pack only (no PV yet) ----
  {
    asm volatile("s_waitcnt vmcnt(4)" ::: "memory");
    __builtin_amdgcn_s_barrier();
    __builtin_amdgcn_sched_barrier(0);
#pragma unroll
    for (int p = 0; p < 2; ++p) {
      g2l16(kS[p], &lds[2 * 8192 + ldst[p]]);
      g2l16(vS[p], &lds[24576 + 2 * 8192 + ldst[p]]);
      kS[p] += 64 * 1536;
      vS[p] += 64;
    }
    const char* Kc = &lds[0];
    short8 kf[2][4];
#pragma unroll
    for (int kk = 0; kk < 2; ++kk)
#pragma unroll
      for (int f = 0; f < 4; ++f) kf[kk][f] = *(const short8*)(Kc + kaddr[kk][f]);
    const f32x4 zf = f32x4{0.f, 0.f, 0.f, 0.f};
    f32x4 w0[4], w1[4];
    __builtin_amdgcn_s_setprio(1);
#pragma unroll
    for (int jf = 0; jf < 4; ++jf)
      w0[jf] = __builtin_amdgcn_mfma_f32_16x16x32_bf16(kf[0][jf], qf[0][0], zf, 0, 0, 0);
#pragma unroll
    for (int jf = 0; jf < 4; ++jf)
      w0[jf] = __builtin_amdgcn_mfma_f32_16x16x32_bf16(kf[1][jf], qf[0][1], w0[jf], 0, 0, 0);
#pragma unroll
    for (int jf = 0; jf < 4; ++jf)
      w1[jf] = __builtin_amdgcn_mfma_f32_16x16x32_bf16(kf[0][jf], qf[1][0], zf, 0, 0, 0);
#pragma unroll
    for (int jf = 0; jf < 4; ++jf)
      w1[jf] = __builtin_amdgcn_mfma_f32_16x16x32_bf16(kf[1][jf], qf[1][1], w1[jf], 0, 0, 0);
    __builtin_amdgcn_s_setprio(0);
#pragma unroll
    for (int jf = 0; jf < 4; ++jf)
#pragma unroll
      for (int r = 0; r < 4; ++r) {
        w0[jf][r] = __builtin_amdgcn_exp2f(w0[jf][r]);
        w1[jf][r] = __builtin_amdgcn_exp2f(w1[jf][r]);
      }
#pragma unroll
    for (int kk = 0; kk < 2; ++kk) {
      pf[0][kk] = mk8(cvtpk(w0[2 * kk][0], w0[2 * kk][1]),
                      cvtpk(w0[2 * kk][2], w0[2 * kk][3]),
                      cvtpk(w0[2 * kk + 1][0], w0[2 * kk + 1][1]),
                      cvtpk(w0[2 * kk + 1][2], w0[2 * kk + 1][3]));
      pf[1][kk] = mk8(cvtpk(w1[2 * kk][0], w1[2 * kk][1]),
                      cvtpk(w1[2 * kk][2], w1[2 * kk][3]),
                      cvtpk(w1[2 * kk + 1][0], w1[2 * kk + 1][1]),
                      cvtpk(w1[2 * kk + 1][2], w1[2 * kk + 1][3]));
    }
#pragma unroll
    for (int kk = 0; kk < 2; ++kk)
#pragma unroll
      for (int f = 0; f < 4; ++f) vfp[kk][f] = *(const short8*)(Kc + vaddr[kk][f]);
  }

  // ---- main loop: compute QK(jt), interleave exp(jt) with PV(jt-1) ----
#pragma unroll 3
  for (int jt = 1; jt < 64; ++jt) {
    const int cur = jt % 3;
    const char* Kc = &lds[cur * 8192];
    if (jt < 63) {
      asm volatile("s_waitcnt vmcnt(4) lgkmcnt(0)" ::: "memory");
    } else {
      asm volatile("s_waitcnt vmcnt(0) lgkmcnt(0)" ::: "memory");
    }
    __builtin_amdgcn_s_barrier();
    __builtin_amdgcn_sched_barrier(0);

    // stage tile jt+2 into buf (jt+2)%3 (safe: all waves passed barrier jt)
    if (jt < 62) {
      int nb = (jt + 2) % 3;
#pragma unroll
      for (int p = 0; p < 2; ++p) {
        g2l16(kS[p], &lds[nb * 8192 + ldst[p]]);
        g2l16(vS[p], &lds[24576 + nb * 8192 + ldst[p]]);
        kS[p] += 64 * 1536;
        vS[p] += 64;
      }
    }

    // K fragments (b128, conflict-free)
    short8 kf[2][4];
#pragma unroll
    for (int kk = 0; kk < 2; ++kk)
#pragma unroll
      for (int f = 0; f < 4; ++f) kf[kk][f] = *(const short8*)(Kc + kaddr[kk][f]);

    // QK^T for both q-tiles (16 MFMA), C folded to const zero
    const f32x4 zf = f32x4{0.f, 0.f, 0.f, 0.f};
    f32x4 w0[4], w1[4];
    __builtin_amdgcn_s_setprio(1);
#pragma unroll
    for (int jf = 0; jf < 4; ++jf)
      w0[jf] = __builtin_amdgcn_mfma_f32_16x16x32_bf16(kf[0][jf], qf[0][0], zf, 0, 0, 0);
#pragma unroll
    for (int jf = 0; jf < 4; ++jf)
      w0[jf] = __builtin_amdgcn_mfma_f32_16x16x32_bf16(kf[1][jf], qf[0][1], w0[jf], 0, 0, 0);
#pragma unroll
    for (int jf = 0; jf < 4; ++jf)
      w1[jf] = __builtin_amdgcn_mfma_f32_16x16x32_bf16(kf[0][jf], qf[1][0], zf, 0, 0, 0);
#pragma unroll
    for (int jf = 0; jf < 4; ++jf)
      w1[jf] = __builtin_amdgcn_mfma_f32_16x16x32_bf16(kf[1][jf], qf[1][1], w1[jf], 0, 0, 0);
    __builtin_amdgcn_sched_barrier(0);  // fence QK above the interleave region

    // ---- interleave region: 32 exp + 8 cvt_pk (trans/VALU) || 20 PV MFMA (prev) ----
#pragma unroll
    for (int jf = 0; jf < 4; ++jf)
#pragma unroll
      for (int r = 0; r < 4; ++r) {
        w0[jf][r] = __builtin_amdgcn_exp2f(w0[jf][r]);
        w1[jf][r] = __builtin_amdgcn_exp2f(w1[jf][r]);
      }
    short8 npf0[2], npf1[2];
#pragma unroll
    for (int kk = 0; kk < 2; ++kk) {
      npf0[kk] = mk8(cvtpk(w0[2 * kk][0], w0[2 * kk][1]),
                     cvtpk(w0[2 * kk][2], w0[2 * kk][3]),
                     cvtpk(w0[2 * kk + 1][0], w0[2 * kk + 1][1]),
                     cvtpk(w0[2 * kk + 1][2], w0[2 * kk + 1][3]));
      npf1[kk] = mk8(cvtpk(w1[2 * kk][0], w1[2 * kk][1]),
                     cvtpk(w1[2 * kk][2], w1[2 * kk][3]),
                     cvtpk(w1[2 * kk + 1][0], w1[2 * kk + 1][1]),
                     cvtpk(w1[2 * kk + 1][2], w1[2 * kk + 1][3]));
    }
#pragma unroll
    for (int qt = 0; qt < 2; ++qt)
#pragma unroll
      for (int kk = 0; kk < 2; ++kk) {
#pragma unroll
        for (int df = 0; df < 4; ++df)
          acc[qt][df] = __builtin_amdgcn_mfma_f32_16x16x32_bf16(pf[qt][kk], vfp[kk][df],
                                                                acc[qt][df], 0, 0, 0);
        lacc[qt] = __builtin_amdgcn_mfma_f32_16x16x32_bf16(pf[qt][kk], onesb, lacc[qt], 0, 0, 0);
      }
    // enforce 1 MFMA : 2 VALU interleave (20 MFMA, 40 VALU in this region)
#pragma unroll
    for (int i = 0; i < 20; ++i) {
      __builtin_amdgcn_sched_group_barrier(0x8, 1, 0);   // 1 MFMA
      __builtin_amdgcn_sched_group_barrier(0x2, 2, 0);   // 2 VALU
    }
    __builtin_amdgcn_sched_barrier(0);
    __builtin_amdgcn_s_setprio(0);

    // commit new P; read V(jt) for next iteration's PV (buffer cur is not
    // restaged until after barrier jt+1 -> loop-top lgkmcnt(0) fences these)
    pf[0][0] = npf0[0]; pf[0][1] = npf0[1];
    pf[1][0] = npf1[0]; pf[1][1] = npf1[1];
#pragma unroll
    for (int kk = 0; kk < 2; ++kk)
#pragma unroll
      for (int f = 0; f < 4; ++f) vfp[kk][f] = *(const short8*)(Kc + vaddr[kk][f]);
  }

  // ---- drain: PV for tile 63 ----
  __builtin_amdgcn_s_setprio(1);
#pragma unroll
  for (int qt = 0; qt < 2; ++qt)
#pragma unroll
    for (int kk = 0; kk < 2; ++kk) {
#pragma unroll
      for (int df = 0; df < 4; ++df)
        acc[qt][df] = __builtin_amdgcn_mfma_f32_16x16x32_bf16(pf[qt][kk], vfp[kk][df],
                                                              acc[qt][df], 0, 0, 0);
      lacc[qt] = __builtin_amdgcn_mfma_f32_16x16x32_bf16(pf[qt][kk], onesb, lacc[qt], 0, 0, 0);
    }
  __builtin_amdgcn_s_setprio(0);

  // epilogue: lacc holds full row sums in acc's C/D layout -> no shuffles
#pragma unroll
  for (int qt = 0; qt < 2; ++qt) {
#pragma unroll
    for (int r = 0; r < 4; ++r) {
      float inv = 1.f / lacc[qt][r];
      int row = q0 + qt * 16 + g * 4 + r;
#pragma unroll
      for (int df = 0; df < 4; ++df)
        aT[((size_t)bb * 4096 + row) * 512 + h * 64 + df * 16 + ln] =
            f2bf(acc[qt][df][r] * inv);
    }
  }
}

// ---------------- launcher ----------------
extern "C" void kernel_launch(void* const* d_in, const int* in_sizes, int n_in,
                              void* d_out, int out_size, void* d_ws, size_t ws_size,
                              hipStream_t stream) {
  const float* x     = (const float*)d_in[0];
  const float* gnw   = (const float*)d_in[1];
  const float* gnb   = (const float*)d_in[2];
  const float* qkvw  = (const float*)d_in[3];
  const float* qkvb  = (const float*)d_in[4];
  const float* projw = (const float*)d_in[5];
  const float* projb = (const float*)d_in[6];
  float* out = (float*)d_out;
  char* ws = (char*)d_ws;

  const size_t OFF_WQ   = 0;
  const size_t OFF_WP   = 1572864;
  const size_t OFF_XN   = 2097152;
  const size_t OFF_XNT  = 10485760;
  const size_t OFF_QKV  = 18874368;
  const size_t OFF_QKVT = 44040192;
  const size_t OFF_AT   = 69206016;
  const size_t OFF_PART = 77594624;
  const size_t OFF_STAT = 77602816;

  unsigned short* wq   = (unsigned short*)(ws + OFF_WQ);
  unsigned short* wp   = (unsigned short*)(ws + OFF_WP);
  unsigned short* xn   = (unsigned short*)(ws + OFF_XN);
  unsigned short* xnT  = (unsigned short*)(ws + OFF_XNT);
  unsigned short* qkv  = (unsigned short*)(ws + OFF_QKV);
  unsigned short* qkvT = (unsigned short*)(ws + OFF_QKVT);
  unsigned short* aT   = (unsigned short*)(ws + OFF_AT);
  float* part  = (float*)(ws + OFF_PART);
  float* stats = (float*)(ws + OFF_STAT);

  k_wgn<<<dim3(2048), dim3(256), 0, stream>>>(qkvw, projw, wq, wp, x, part);
  k_gnfin<<<dim3(1), dim3(64), 0, stream>>>(part, stats);
  k_gnnorm<<<dim3(64, 8, 2), dim3(256), 0, stream>>>(x, gnw, gnb, stats, xn, xnT);
  k_gemm<0><<<dim3(32, 12, 2), dim3(256), 0, stream>>>(wq, xnT, qkvb, qkv, qkvT, nullptr, nullptr, 1536);
  k_attn<<<dim3(32, 8, 2), dim3(256), 0, stream>>>(qkv, qkvT, aT);
  k_gemm<1><<<dim3(32, 4, 2), dim3(256), 0, stream>>>(wp, aT, projb, nullptr, nullptr, xn, out, 512);
}